// Round 1
// baseline (1467.872 us; speedup 1.0000x reference)
//
#include <hip/hip_runtime.h>
#include <math.h>

// Problem constants (from reference setup_inputs)
constexpr int Bn = 4, Cc = 128, On = 128, Hh = 160, Ww = 160, Kk = 9;
constexpr int HW = Hh * Ww;          // 25600
constexpr int PIX = 64;              // pixels per block (main kernel)
constexpr int CCH = 32;              // channel chunk

// ---------------------------------------------------------------------------
// Kernel 0: transpose main-conv weights (O,C,3,3) -> [k][c][o] for coalesced
// GEMM staging.
// ---------------------------------------------------------------------------
__global__ void transpose_w(const float* __restrict__ wt, float* __restrict__ wtr) {
    int idx = blockIdx.x * 256 + threadIdx.x;        // K*C*O = 147456
    if (idx >= Kk * Cc * On) return;
    int o = idx % On;
    int c = (idx / On) % Cc;
    int k = idx / (On * Cc);
    wtr[idx] = wt[(o * Cc + c) * 9 + k];
}

// ---------------------------------------------------------------------------
// Kernel 1: offset (18ch) + mask (9ch) 3x3 convs. One thread per pixel,
// 27 accumulators; weight loads are wave-uniform -> scalar loads.
// Outputs dy, dx, mask(after sigmoid) as [b][k][hw].
// ---------------------------------------------------------------------------
__global__ __launch_bounds__(64) void offmask_kernel(
    const float* __restrict__ x,
    const float* __restrict__ w_off, const float* __restrict__ b_off,
    const float* __restrict__ w_mask, const float* __restrict__ b_mask,
    float* __restrict__ dy_o, float* __restrict__ dx_o, float* __restrict__ mk_o)
{
    int p = blockIdx.x * 64 + threadIdx.x;           // 0..HW-1
    int b = blockIdx.y;
    int h = p / Ww, w = p % Ww;
    float acc[27];
#pragma unroll
    for (int i = 0; i < 27; ++i) acc[i] = 0.f;
    const float* xb = x + (size_t)b * Cc * HW;

    for (int c = 0; c < Cc; ++c) {
        const float* xc = xb + (size_t)c * HW;
        float win[9];
#pragma unroll
        for (int r = 0; r < 3; ++r) {
            int hh = h + r - 1;
            bool okh = (unsigned)hh < (unsigned)Hh;
#pragma unroll
            for (int s = 0; s < 3; ++s) {
                int ww2 = w + s - 1;
                bool ok = okh && ((unsigned)ww2 < (unsigned)Ww);
                win[r * 3 + s] = ok ? xc[hh * Ww + ww2] : 0.f;
            }
        }
        const float* wo = w_off + c * 9;             // + ch*C*9 + t
#pragma unroll
        for (int ch = 0; ch < 18; ++ch) {
#pragma unroll
            for (int t = 0; t < 9; ++t)
                acc[ch] = fmaf(wo[ch * Cc * 9 + t], win[t], acc[ch]);
        }
        const float* wm = w_mask + c * 9;
#pragma unroll
        for (int ch = 0; ch < 9; ++ch) {
#pragma unroll
            for (int t = 0; t < 9; ++t)
                acc[18 + ch] = fmaf(wm[ch * Cc * 9 + t], win[t], acc[18 + ch]);
        }
    }

#pragma unroll
    for (int k = 0; k < 9; ++k) {
        float dy = acc[2 * k]     + b_off[2 * k];
        float dx = acc[2 * k + 1] + b_off[2 * k + 1];
        float mm = acc[18 + k]    + b_mask[k];
        mm = 1.f / (1.f + expf(-mm));
        size_t base = (size_t)(b * 9 + k) * HW + p;
        dy_o[base] = dy;
        dx_o[base] = dx;
        mk_o[base] = mm;
    }
}

// ---------------------------------------------------------------------------
// Kernel 2: main deformable conv. Block: 256 threads, 64 pixels x all 128 o.
// Per (k, c-chunk of 32): stage bilinear-gathered val[32][64] and weights
// w[32][128] in LDS, then register-tiled 8o x 4p outer product.
// ---------------------------------------------------------------------------
__global__ __launch_bounds__(256) void dconv_main(
    const float* __restrict__ x,
    const float* __restrict__ wtr,   // [K][C][O]
    const float* __restrict__ bias,  // [O]
    const float* __restrict__ dy_i, const float* __restrict__ dx_i,
    const float* __restrict__ mk_i,
    float* __restrict__ out)
{
    __shared__ float wgt_s[4][PIX];
    __shared__ int   idx_s[4][PIX];
    __shared__ float w_s[CCH * On];      // [cl][o] flat, 16 KB
    __shared__ float val_s[CCH][PIX];    // 8 KB

    const int t    = threadIdx.x;
    const int tile = blockIdx.x;
    const int b    = blockIdx.y;
    const int p0   = tile * PIX;
    const int to   = t & 15;             // o group: o = to*8 .. +8
    const int tp   = t >> 4;             // p group: p = tp*4 .. +4
    const int lane = t & 63;
    const int wv4  = t >> 6;             // wave id 0..3

    float acc[8][4];
#pragma unroll
    for (int i = 0; i < 8; ++i)
#pragma unroll
        for (int j = 0; j < 4; ++j) acc[i][j] = 0.f;

    const float* xb = x + (size_t)b * Cc * HW;

    for (int k = 0; k < Kk; ++k) {
        // ---- bilinear setup for the 64 pixels (threads 0..63) ----
        if (t < PIX) {
            int p = p0 + t;
            int h = p / Ww, w = p % Ww;
            size_t base = (size_t)(b * 9 + k) * HW + p;
            float dy = dy_i[base], dx = dx_i[base], m = mk_i[base];
            float py = (float)(h + (k / 3) - 1) + dy;
            float px = (float)(w + (k % 3) - 1) + dx;
            float y0f = floorf(py), x0f = floorf(px);
            float ly = py - y0f, lx = px - x0f;
            int y0 = (int)y0f, x0 = (int)x0f;
#pragma unroll
            for (int cr = 0; cr < 4; ++cr) {
                int iy = y0 + (cr >> 1), ix = x0 + (cr & 1);
                bool ok = ((unsigned)iy < (unsigned)Hh) && ((unsigned)ix < (unsigned)Ww);
                float wy = (cr >> 1) ? ly : (1.f - ly);
                float wx = (cr & 1) ? lx : (1.f - lx);
                int cy = min(max(iy, 0), Hh - 1);
                int cx = min(max(ix, 0), Ww - 1);
                idx_s[cr][t] = cy * Ww + cx;
                wgt_s[cr][t] = ok ? (wy * wx * m) : 0.f;
            }
        }
        __syncthreads();

        for (int cc = 0; cc < Cc; cc += CCH) {
            // ---- stage weights: w_s[cl*128+o] = wtr[(k*C+cc+cl)*O + o] ----
            {
                const float4* src = (const float4*)(wtr + ((size_t)k * Cc + cc) * On);
                float4* dst = (float4*)w_s;
#pragma unroll
                for (int i = 0; i < 4; ++i)
                    dst[i * 256 + t] = src[i * 256 + t];
            }
            // ---- stage vals: wave-contiguous pixels, one channel per iter ----
            {
                float wg0 = wgt_s[0][lane], wg1 = wgt_s[1][lane];
                float wg2 = wgt_s[2][lane], wg3 = wgt_s[3][lane];
                int i0 = idx_s[0][lane], i1 = idx_s[1][lane];
                int i2 = idx_s[2][lane], i3 = idx_s[3][lane];
#pragma unroll
                for (int i = 0; i < 8; ++i) {
                    int cl = wv4 + (i << 2);
                    const float* xc = xb + (size_t)(cc + cl) * HW;
                    float v = wg0 * xc[i0];
                    v = fmaf(wg1, xc[i1], v);
                    v = fmaf(wg2, xc[i2], v);
                    v = fmaf(wg3, xc[i3], v);
                    val_s[cl][lane] = v;
                }
            }
            __syncthreads();

            // ---- register-tiled MAC: acc[8o][4p] ----
#pragma unroll
            for (int cl = 0; cl < CCH; ++cl) {
                float4 vv = *(const float4*)(&val_s[cl][tp << 2]);
                float4 w0 = *(const float4*)(&w_s[cl * On + (to << 3)]);
                float4 w1 = *(const float4*)(&w_s[cl * On + (to << 3) + 4]);
                float wv[8] = {w0.x, w0.y, w0.z, w0.w, w1.x, w1.y, w1.z, w1.w};
                float pv[4] = {vv.x, vv.y, vv.z, vv.w};
#pragma unroll
                for (int oi = 0; oi < 8; ++oi)
#pragma unroll
                    for (int pi = 0; pi < 4; ++pi)
                        acc[oi][pi] = fmaf(wv[oi], pv[pi], acc[oi][pi]);
            }
            __syncthreads();
        }
    }

    // ---- epilogue: add bias, float4 stores ----
#pragma unroll
    for (int oi = 0; oi < 8; ++oi) {
        int o = (to << 3) + oi;
        float bo = bias[o];
        float4 r;
        r.x = acc[oi][0] + bo;
        r.y = acc[oi][1] + bo;
        r.z = acc[oi][2] + bo;
        r.w = acc[oi][3] + bo;
        *(float4*)(out + ((size_t)(b * On + o)) * HW + p0 + (tp << 2)) = r;
    }
}

// ---------------------------------------------------------------------------
extern "C" void kernel_launch(void* const* d_in, const int* in_sizes, int n_in,
                              void* d_out, int out_size, void* d_ws, size_t ws_size,
                              hipStream_t stream) {
    const float* x      = (const float*)d_in[0];
    const float* w_off  = (const float*)d_in[1];
    const float* b_off  = (const float*)d_in[2];
    const float* w_mask = (const float*)d_in[3];
    const float* b_mask = (const float*)d_in[4];
    const float* wt     = (const float*)d_in[5];
    const float* bias   = (const float*)d_in[6];
    float* out = (float*)d_out;

    float* ws  = (float*)d_ws;
    float* wtr = ws;                          // K*C*O = 147456 floats
    float* dy  = wtr + Kk * Cc * On;          // B*K*HW = 921600 floats
    float* dx  = dy + Bn * Kk * HW;
    float* mk  = dx + Bn * Kk * HW;
    // total ws use: (147456 + 3*921600)*4 B ~= 11.1 MB

    transpose_w<<<(Kk * Cc * On + 255) / 256, 256, 0, stream>>>(wt, wtr);
    offmask_kernel<<<dim3(HW / 64, Bn), 64, 0, stream>>>(
        x, w_off, b_off, w_mask, b_mask, dy, dx, mk);
    dconv_main<<<dim3(HW / PIX, Bn), 256, 0, stream>>>(
        x, wtr, bias, dy, dx, mk, out);
}

// Round 2
// 619.734 us; speedup vs baseline: 2.3686x; 2.3686x over previous
//
#include <hip/hip_runtime.h>
#include <math.h>

constexpr int Bn = 4, Cc = 128, On = 128, Hh = 160, Ww = 160, Kk = 9;
constexpr int HW = Hh * Ww;          // 25600

typedef __attribute__((ext_vector_type(8))) short s16x8;
typedef __attribute__((ext_vector_type(4))) float f32x4;

__device__ inline float bf2f(short s) {
    union { float f; unsigned u; } v;
    v.u = ((unsigned)(unsigned short)s) << 16;
    return v.f;
}
__device__ inline short f2bf(float f) {
    union { float f; unsigned u; } v;
    v.f = f;
    unsigned r = v.u + 0x7fffu + ((v.u >> 16) & 1u);   // RNE
    return (short)(r >> 16);
}

// ---------------------------------------------------------------------------
// Kernel A1: x (NCHW f32) -> xT (NHWC bf16). Per block: 64 px x 128 c.
// ---------------------------------------------------------------------------
__global__ __launch_bounds__(256) void to_nhwc(const float* __restrict__ x,
                                               short* __restrict__ xT) {
    __shared__ float tile[128][65];
    const int t = threadIdx.x;
    const int p0 = blockIdx.x * 64;
    const int b = blockIdx.y;
#pragma unroll
    for (int i = 0; i < 32; ++i) {
        int c = i * 4 + (t >> 6);
        tile[c][t & 63] = x[((size_t)b * Cc + c) * HW + p0 + (t & 63)];
    }
    __syncthreads();
    const int px = t >> 2, cq = t & 3;
    short* dst = xT + ((size_t)(b * HW) + p0 + px) * Cc;
#pragma unroll
    for (int j = 0; j < 8; ++j) {
        int c0 = cq * 4 + j * 16;
        short4 v;
        v.x = f2bf(tile[c0 + 0][px]);
        v.y = f2bf(tile[c0 + 1][px]);
        v.z = f2bf(tile[c0 + 2][px]);
        v.w = f2bf(tile[c0 + 3][px]);
        *(short4*)(dst + c0) = v;
    }
}

// ---------------------------------------------------------------------------
// Kernel A2: wt (O,C,3,3) f32 -> wb[k][o][c] bf16
// ---------------------------------------------------------------------------
__global__ void prep_w(const float* __restrict__ wt, short* __restrict__ wb) {
    int idx = blockIdx.x * 256 + threadIdx.x;     // K*O*C = 147456
    if (idx >= Kk * On * Cc) return;
    int c = idx & 127;
    int o = (idx >> 7) & 127;
    int k = idx >> 14;
    wb[idx] = f2bf(wt[(o * Cc + c) * 9 + k]);
}

// ---------------------------------------------------------------------------
// Kernel B: offset/mask convs. 256 thr = 64 px x 4 channel-groups of 32.
// ---------------------------------------------------------------------------
__global__ __launch_bounds__(256) void offmask_kernel(
    const float* __restrict__ x,
    const float* __restrict__ w_off, const float* __restrict__ b_off,
    const float* __restrict__ w_mask, const float* __restrict__ b_mask,
    float* __restrict__ dy_o, float* __restrict__ dx_o, float* __restrict__ mk_o)
{
    __shared__ float red_s[4][27][64];
    const int t = threadIdx.x;
    const int px = t & 63, cg = t >> 6;
    const int p = blockIdx.x * 64 + px;
    const int b = blockIdx.y;
    const int h = p / Ww, w = p % Ww;

    float acc[27];
#pragma unroll
    for (int i = 0; i < 27; ++i) acc[i] = 0.f;

    const float* xb = x + ((size_t)b * Cc + cg * 32) * HW;
    for (int c = 0; c < 32; ++c) {
        const float* xc = xb + (size_t)c * HW;
        float win[9];
#pragma unroll
        for (int r = 0; r < 3; ++r) {
            int hh = h + r - 1;
            bool okh = (unsigned)hh < (unsigned)Hh;
#pragma unroll
            for (int s = 0; s < 3; ++s) {
                int ww2 = w + s - 1;
                bool ok = okh && ((unsigned)ww2 < (unsigned)Ww);
                win[r * 3 + s] = ok ? xc[hh * Ww + ww2] : 0.f;
            }
        }
        int cglob = cg * 32 + c;
        const float* wo = w_off + cglob * 9;
#pragma unroll
        for (int ch = 0; ch < 18; ++ch)
#pragma unroll
            for (int tt = 0; tt < 9; ++tt)
                acc[ch] = fmaf(wo[ch * Cc * 9 + tt], win[tt], acc[ch]);
        const float* wm = w_mask + cglob * 9;
#pragma unroll
        for (int ch = 0; ch < 9; ++ch)
#pragma unroll
            for (int tt = 0; tt < 9; ++tt)
                acc[18 + ch] = fmaf(wm[ch * Cc * 9 + tt], win[tt], acc[18 + ch]);
    }
#pragma unroll
    for (int j = 0; j < 27; ++j) red_s[cg][j][px] = acc[j];
    __syncthreads();

#pragma unroll
    for (int i = 0; i < 7; ++i) {
        int j = cg + i * 4;
        if (j >= 27) break;
        float s = red_s[0][j][px] + red_s[1][j][px] + red_s[2][j][px] + red_s[3][j][px];
        if (j < 18) {
            int k = j >> 1;
            float v = s + b_off[j];
            size_t base = (size_t)(b * 9 + k) * HW + p;
            if ((j & 1) == 0) dy_o[base] = v; else dx_o[base] = v;
        } else {
            int k = j - 18;
            float v = s + b_mask[k];
            mk_o[(size_t)(b * 9 + k) * HW + p] = 1.f / (1.f + expf(-v));
        }
    }
}

// ---------------------------------------------------------------------------
// Kernel C: main deformable conv with bf16 MFMA.
// Block: 256 thr (4 waves), 64 px x all 128 o.
// Per k: bilinear setup -> stage w[k][o][c] (swizzled) -> gather val[px][c]
// (NHWC, coalesced, swizzled LDS) -> mfma_f32_16x16x32_bf16 accumulate.
// ---------------------------------------------------------------------------
__global__ __launch_bounds__(256) void dconv_main(
    const short* __restrict__ xT,    // [b][hw][c] bf16
    const short* __restrict__ wb,    // [k][o][c] bf16
    const float* __restrict__ bias,
    const float* __restrict__ dy_i, const float* __restrict__ dx_i,
    const float* __restrict__ mk_i,
    float* __restrict__ out)
{
    __shared__ short w_lds[128 * 128];   // 32 KB, byte ^= (o&7)<<4
    __shared__ short val_lds[64 * 128];  // 16 KB, byte ^= (px&7)<<4
    __shared__ float wgt_s[4][64];
    __shared__ int   idx_s[4][64];

    const int t = threadIdx.x;
    const int b = blockIdx.y;
    const int p0 = blockIdx.x * 64;
    const int lane = t & 63;
    const int wid = t >> 6;
    const int pm = wid * 16;             // wave's pixel base

    f32x4 acc[8];
#pragma unroll
    for (int i = 0; i < 8; ++i) acc[i] = (f32x4){0.f, 0.f, 0.f, 0.f};

    const short* xb = xT + (size_t)b * HW * Cc + (lane & 31) * 4;

    for (int k = 0; k < Kk; ++k) {
        // ---- 1. bilinear setup (threads 0..63) ----
        if (t < 64) {
            int p = p0 + t;
            int h = p / Ww, w = p % Ww;
            size_t base = (size_t)(b * 9 + k) * HW + p;
            float dyv = dy_i[base], dxv = dx_i[base], m = mk_i[base];
            float py = (float)(h + (k / 3) - 1) + dyv;
            float pxf = (float)(w + (k % 3) - 1) + dxv;
            float y0f = floorf(py), x0f = floorf(pxf);
            float ly = py - y0f, lx = pxf - x0f;
            int y0 = (int)y0f, x0 = (int)x0f;
#pragma unroll
            for (int cr = 0; cr < 4; ++cr) {
                int iy = y0 + (cr >> 1), ix = x0 + (cr & 1);
                bool ok = ((unsigned)iy < (unsigned)Hh) && ((unsigned)ix < (unsigned)Ww);
                float wy = (cr >> 1) ? ly : (1.f - ly);
                float wx = (cr & 1) ? lx : (1.f - lx);
                int cy = min(max(iy, 0), Hh - 1);
                int cx = min(max(ix, 0), Ww - 1);
                idx_s[cr][t] = cy * Ww + cx;
                wgt_s[cr][t] = ok ? (wy * wx * m) : 0.f;
            }
        }
        // ---- 2. stage weights for this k (all threads) ----
        {
            const int4* src = (const int4*)(wb + (size_t)k * 128 * 128);
#pragma unroll
            for (int i = 0; i < 8; ++i) {
                int ci = i * 256 + t;            // 16B chunk id, 0..2047
                int o = ci >> 4;                 // 16 chunks per o-row
                int byte = (ci << 4) ^ ((o & 7) << 4);
                *(int4*)((char*)w_lds + byte) = src[ci];
            }
        }
        __syncthreads();

        // ---- 3. gather into val_lds: wave = 16 px; lane = (px pair, c-quad) ----
        {
            const int cq = lane & 31;
#pragma unroll
            for (int pp = 0; pp < 16; pp += 2) {
                int pxl = pm + pp + (lane >> 5);
                float w0 = wgt_s[0][pxl], w1 = wgt_s[1][pxl];
                float w2 = wgt_s[2][pxl], w3 = wgt_s[3][pxl];
                size_t i0 = (size_t)idx_s[0][pxl] * Cc;
                size_t i1 = (size_t)idx_s[1][pxl] * Cc;
                size_t i2 = (size_t)idx_s[2][pxl] * Cc;
                size_t i3 = (size_t)idx_s[3][pxl] * Cc;
                short4 v0 = *(const short4*)(xb + i0);
                short4 v1 = *(const short4*)(xb + i1);
                short4 v2 = *(const short4*)(xb + i2);
                short4 v3 = *(const short4*)(xb + i3);
                float s0 = w0 * bf2f(v0.x) + w1 * bf2f(v1.x) + w2 * bf2f(v2.x) + w3 * bf2f(v3.x);
                float s1 = w0 * bf2f(v0.y) + w1 * bf2f(v1.y) + w2 * bf2f(v2.y) + w3 * bf2f(v3.y);
                float s2 = w0 * bf2f(v0.z) + w1 * bf2f(v1.z) + w2 * bf2f(v2.z) + w3 * bf2f(v3.z);
                float s3 = w0 * bf2f(v0.w) + w1 * bf2f(v1.w) + w2 * bf2f(v2.w) + w3 * bf2f(v3.w);
                short4 r;
                r.x = f2bf(s0); r.y = f2bf(s1); r.z = f2bf(s2); r.w = f2bf(s3);
                int byte = (pxl * 256 + cq * 8) ^ ((pxl & 7) << 4);
                *(short4*)((char*)val_lds + byte) = r;
            }
        }
        __syncthreads();

        // ---- 4. MFMA: wave computes px[pm..pm+15] x o[0..127] ----
        {
            s16x8 afr[4];
            const int pxr = pm + (lane & 15);
            const int kb = (lane >> 4) * 8;       // k-slice base within 32
#pragma unroll
            for (int kk = 0; kk < 4; ++kk) {
                int byte = (pxr * 256 + (kk * 32 + kb) * 2) ^ ((pxr & 7) << 4);
                afr[kk] = *(const s16x8*)((char*)val_lds + byte);
            }
            const int orow = lane & 15;
#pragma unroll
            for (int ot = 0; ot < 8; ++ot) {
                int o = ot * 16 + orow;
#pragma unroll
                for (int kk = 0; kk < 4; ++kk) {
                    int byte = (o * 256 + (kk * 32 + kb) * 2) ^ ((o & 7) << 4);
                    s16x8 bfr = *(const s16x8*)((char*)w_lds + byte);
                    acc[ot] = __builtin_amdgcn_mfma_f32_16x16x32_bf16(afr[kk], bfr, acc[ot], 0, 0, 0);
                }
            }
        }
        __syncthreads();
    }

    // ---- epilogue: D layout col=lane&15 (o), row=(lane>>4)*4+reg (px) ----
#pragma unroll
    for (int ot = 0; ot < 8; ++ot) {
        int o = ot * 16 + (lane & 15);
        float bo = bias[o];
        float4 r;
        r.x = acc[ot][0] + bo;
        r.y = acc[ot][1] + bo;
        r.z = acc[ot][2] + bo;
        r.w = acc[ot][3] + bo;
        *(float4*)(out + ((size_t)(b * On + o)) * HW + p0 + pm + (lane >> 4) * 4) = r;
    }
}

// ---------------------------------------------------------------------------
extern "C" void kernel_launch(void* const* d_in, const int* in_sizes, int n_in,
                              void* d_out, int out_size, void* d_ws, size_t ws_size,
                              hipStream_t stream) {
    const float* x      = (const float*)d_in[0];
    const float* w_off  = (const float*)d_in[1];
    const float* b_off  = (const float*)d_in[2];
    const float* w_mask = (const float*)d_in[3];
    const float* b_mask = (const float*)d_in[4];
    const float* wt     = (const float*)d_in[5];
    const float* bias   = (const float*)d_in[6];
    float* out = (float*)d_out;

    short* xT = (short*)d_ws;                       // B*HW*C bf16 = 26.2 MB
    short* wb = xT + (size_t)Bn * HW * Cc;          // K*O*C bf16 = 0.29 MB
    float* dy = (float*)(wb + Kk * On * Cc);        // B*9*HW f32
    float* dx = dy + (size_t)Bn * 9 * HW;
    float* mk = dx + (size_t)Bn * 9 * HW;
    // total ws: ~37.6 MB

    to_nhwc<<<dim3(HW / 64, Bn), 256, 0, stream>>>(x, xT);
    prep_w<<<(Kk * On * Cc + 255) / 256, 256, 0, stream>>>(wt, wb);
    offmask_kernel<<<dim3(HW / 64, Bn), 256, 0, stream>>>(
        x, w_off, b_off, w_mask, b_mask, dy, dx, mk);
    dconv_main<<<dim3(HW / 64, Bn), 256, 0, stream>>>(
        xT, wb, bias, dy, dx, mk, out);
}

// Round 3
// 378.097 us; speedup vs baseline: 3.8823x; 1.6391x over previous
//
#include <hip/hip_runtime.h>
#include <math.h>

constexpr int Bn = 4, Cc = 128, On = 128, Hh = 160, Ww = 160, Kk = 9;
constexpr int HW = Hh * Ww;          // 25600

typedef __attribute__((ext_vector_type(8))) short s16x8;
typedef __attribute__((ext_vector_type(4))) float f32x4;

__device__ inline float bf2f(short s) {
    union { float f; unsigned u; } v;
    v.u = ((unsigned)(unsigned short)s) << 16;
    return v.f;
}
__device__ inline short f2bf(float f) {
    union { float f; unsigned u; } v;
    v.f = f;
    unsigned r = v.u + 0x7fffu + ((v.u >> 16) & 1u);   // RNE
    return (short)(r >> 16);
}

// ---------------------------------------------------------------------------
// Kernel A1: x (NCHW f32) -> xT (NHWC bf16 hi) + xLo (NHWC bf16 lo).
// ---------------------------------------------------------------------------
__global__ __launch_bounds__(256) void to_nhwc(const float* __restrict__ x,
                                               short* __restrict__ xT,
                                               short* __restrict__ xLo) {
    __shared__ float tile[128][65];
    const int t = threadIdx.x;
    const int p0 = blockIdx.x * 64;
    const int b = blockIdx.y;
#pragma unroll
    for (int i = 0; i < 32; ++i) {
        int c = i * 4 + (t >> 6);
        tile[c][t & 63] = x[((size_t)b * Cc + c) * HW + p0 + (t & 63)];
    }
    __syncthreads();
    const int px = t >> 2, cq = t & 3;
    short* dsth = xT  + ((size_t)(b * HW) + p0 + px) * Cc;
    short* dstl = xLo + ((size_t)(b * HW) + p0 + px) * Cc;
#pragma unroll
    for (int j = 0; j < 8; ++j) {
        int c0 = cq * 4 + j * 16;
        short4 vh, vl;
        float f0 = tile[c0 + 0][px], f1 = tile[c0 + 1][px];
        float f2 = tile[c0 + 2][px], f3 = tile[c0 + 3][px];
        vh.x = f2bf(f0); vh.y = f2bf(f1); vh.z = f2bf(f2); vh.w = f2bf(f3);
        vl.x = f2bf(f0 - bf2f(vh.x));
        vl.y = f2bf(f1 - bf2f(vh.y));
        vl.z = f2bf(f2 - bf2f(vh.z));
        vl.w = f2bf(f3 - bf2f(vh.w));
        *(short4*)(dsth + c0) = vh;
        *(short4*)(dstl + c0) = vl;
    }
}

// ---------------------------------------------------------------------------
// Kernel A2: wt (O,C,3,3) f32 -> wb[k][o][c] bf16
// ---------------------------------------------------------------------------
__global__ void prep_w(const float* __restrict__ wt, short* __restrict__ wb) {
    int idx = blockIdx.x * 256 + threadIdx.x;     // K*O*C = 147456
    if (idx >= Kk * On * Cc) return;
    int c = idx & 127;
    int o = (idx >> 7) & 127;
    int k = idx >> 14;
    wb[idx] = f2bf(wt[(o * Cc + c) * 9 + k]);
}

// ---------------------------------------------------------------------------
// Kernel A3: offset/mask weights -> wofm_{hi,lo}[k][ch32][c].
// ch 0..17 = offset rows (even=dy_k, odd=dx_k, k=ch>>1); 18..26 = mask; 27..31 = 0.
// ---------------------------------------------------------------------------
__global__ void prep_wofm(const float* __restrict__ w_off,
                          const float* __restrict__ w_mask,
                          short* __restrict__ wh, short* __restrict__ wl) {
    int idx = blockIdx.x * 256 + threadIdx.x;     // 9*32*128 = 36864
    if (idx >= Kk * 32 * Cc) return;
    int c = idx & 127;
    int ch = (idx >> 7) & 31;
    int k = idx >> 12;
    float v = 0.f;
    if (ch < 18)      v = w_off[(ch * Cc + c) * 9 + k];
    else if (ch < 27) v = w_mask[((ch - 18) * Cc + c) * 9 + k];
    short hi = f2bf(v);
    wh[idx] = hi;
    wl[idx] = f2bf(v - bf2f(hi));
}

// ---------------------------------------------------------------------------
// Kernel B: offset/mask conv via MFMA with bf16 hi/lo split.
// Block: 4 output rows x 16 cols; 4 waves, wave wid = row h0+wid.
// Stage 6 source rows x 18 px x 128 c (hi+lo) in swizzled LDS; ONE sync;
// per tap: A from LDS, B (weights) straight from L2-resident global.
// ---------------------------------------------------------------------------
__global__ __launch_bounds__(256) void offmask_mfma(
    const short* __restrict__ xT, const short* __restrict__ xLo,
    const short* __restrict__ wh, const short* __restrict__ wl,
    const float* __restrict__ b_off, const float* __restrict__ b_mask,
    float* __restrict__ dy_o, float* __restrict__ dx_o, float* __restrict__ mk_o)
{
    __shared__ short a_hi[6][2304];   // [slot][18px * 128c], row stride 256 B
    __shared__ short a_lo[6][2304];

    const int t = threadIdx.x;
    const int w0 = blockIdx.x * 16;
    const int h0 = blockIdx.y * 4;
    const int b = blockIdx.z;

    // ---- stage 6 source rows (h0-1 .. h0+4), cols w0-1 .. w0+16 ----
    const short* xh_b = xT  + (size_t)b * HW * Cc;
    const short* xl_b = xLo + (size_t)b * HW * Cc;
#pragma unroll
    for (int j = 0; j < 14; ++j) {
        int ci = j * 256 + t;                 // 6 slots * 2(hi/lo) * 288 chunks
        if (ci < 3456) {
            int slot = ci / 576;
            int rem  = ci % 576;
            int isLo = rem >= 288;
            int cj   = isLo ? rem - 288 : rem;
            int pxl  = cj >> 4;               // 0..17
            int ck   = cj & 15;               // 16B chunk within 256B row
            int r   = h0 - 1 + slot;
            int col = w0 - 1 + pxl;
            int4 v = make_int4(0, 0, 0, 0);
            if ((unsigned)r < (unsigned)Hh && (unsigned)col < (unsigned)Ww) {
                const short* src = (isLo ? xl_b : xh_b) +
                                   ((size_t)(r * Ww + col)) * Cc + ck * 8;
                v = *(const int4*)src;
            }
            int byte = (pxl * 256 + ck * 16) ^ ((pxl & 7) << 4);
            *(int4*)((char*)(isLo ? a_lo[slot] : a_hi[slot]) + byte) = v;
        }
    }
    __syncthreads();

    const int lane = t & 63, wid = t >> 6;
    const int i  = lane & 15;
    const int kb = (lane >> 4) * 8;

    f32x4 acc[2];
    acc[0] = (f32x4){0.f, 0.f, 0.f, 0.f};
    acc[1] = (f32x4){0.f, 0.f, 0.f, 0.f};

#pragma unroll
    for (int ky = 0; ky < 3; ++ky) {
        const int slot = wid + ky;            // source row = h0+wid+ky-1
#pragma unroll
        for (int kxi = 0; kxi < 3; ++kxi) {
            const int pxl = i + kxi;          // col within staged row
            s16x8 ah[4], al[4];
#pragma unroll
            for (int kk = 0; kk < 4; ++kk) {
                int byte = (pxl * 256 + (kk * 32 + kb) * 2) ^ ((pxl & 7) << 4);
                ah[kk] = *(const s16x8*)((char*)a_hi[slot] + byte);
                al[kk] = *(const s16x8*)((char*)a_lo[slot] + byte);
            }
            const int k = ky * 3 + kxi;
#pragma unroll
            for (int tile = 0; tile < 2; ++tile) {
                const short* bp = wh + ((size_t)k * 32 + tile * 16 + i) * Cc + kb;
                const short* lp = wl + ((size_t)k * 32 + tile * 16 + i) * Cc + kb;
                s16x8 bh[4], bl[4];
#pragma unroll
                for (int kk = 0; kk < 4; ++kk) {
                    bh[kk] = *(const s16x8*)(bp + kk * 32);
                    bl[kk] = *(const s16x8*)(lp + kk * 32);
                }
#pragma unroll
                for (int kk = 0; kk < 4; ++kk) {
                    acc[tile] = __builtin_amdgcn_mfma_f32_16x16x32_bf16(ah[kk], bh[kk], acc[tile], 0, 0, 0);
                    acc[tile] = __builtin_amdgcn_mfma_f32_16x16x32_bf16(al[kk], bh[kk], acc[tile], 0, 0, 0);
                    acc[tile] = __builtin_amdgcn_mfma_f32_16x16x32_bf16(ah[kk], bl[kk], acc[tile], 0, 0, 0);
                }
            }
        }
    }

    // ---- epilogue: D col=lane&15 -> ch, row=(lane>>4)*4+reg -> px ----
    const int hr = h0 + wid;
#pragma unroll
    for (int tile = 0; tile < 2; ++tile) {
        int ch = tile * 16 + i;
#pragma unroll
        for (int reg = 0; reg < 4; ++reg) {
            int pxo = (lane >> 4) * 4 + reg;
            int p = hr * Ww + w0 + pxo;
            float v = acc[tile][reg];
            if (ch < 18) {
                int k = ch >> 1;
                v += b_off[ch];
                if (ch & 1) dx_o[(size_t)(b * 9 + k) * HW + p] = v;
                else        dy_o[(size_t)(b * 9 + k) * HW + p] = v;
            } else if (ch < 27) {
                int k = ch - 18;
                v += b_mask[k];
                mk_o[(size_t)(b * 9 + k) * HW + p] = 1.f / (1.f + expf(-v));
            }
        }
    }
}

// ---------------------------------------------------------------------------
// Kernel C: main deformable conv with bf16 MFMA (unchanged from round 2).
// ---------------------------------------------------------------------------
__global__ __launch_bounds__(256) void dconv_main(
    const short* __restrict__ xT,    // [b][hw][c] bf16
    const short* __restrict__ wb,    // [k][o][c] bf16
    const float* __restrict__ bias,
    const float* __restrict__ dy_i, const float* __restrict__ dx_i,
    const float* __restrict__ mk_i,
    float* __restrict__ out)
{
    __shared__ short w_lds[128 * 128];   // 32 KB, byte ^= (o&7)<<4
    __shared__ short val_lds[64 * 128];  // 16 KB, byte ^= (px&7)<<4
    __shared__ float wgt_s[4][64];
    __shared__ int   idx_s[4][64];

    const int t = threadIdx.x;
    const int b = blockIdx.y;
    const int p0 = blockIdx.x * 64;
    const int lane = t & 63;
    const int wid = t >> 6;
    const int pm = wid * 16;             // wave's pixel base

    f32x4 acc[8];
#pragma unroll
    for (int i = 0; i < 8; ++i) acc[i] = (f32x4){0.f, 0.f, 0.f, 0.f};

    const short* xb = xT + (size_t)b * HW * Cc + (lane & 31) * 4;

    for (int k = 0; k < Kk; ++k) {
        // ---- 1. bilinear setup (threads 0..63) ----
        if (t < 64) {
            int p = p0 + t;
            int h = p / Ww, w = p % Ww;
            size_t base = (size_t)(b * 9 + k) * HW + p;
            float dyv = dy_i[base], dxv = dx_i[base], m = mk_i[base];
            float py = (float)(h + (k / 3) - 1) + dyv;
            float pxf = (float)(w + (k % 3) - 1) + dxv;
            float y0f = floorf(py), x0f = floorf(pxf);
            float ly = py - y0f, lx = pxf - x0f;
            int y0 = (int)y0f, x0 = (int)x0f;
#pragma unroll
            for (int cr = 0; cr < 4; ++cr) {
                int iy = y0 + (cr >> 1), ix = x0 + (cr & 1);
                bool ok = ((unsigned)iy < (unsigned)Hh) && ((unsigned)ix < (unsigned)Ww);
                float wy = (cr >> 1) ? ly : (1.f - ly);
                float wx = (cr & 1) ? lx : (1.f - lx);
                int cy = min(max(iy, 0), Hh - 1);
                int cx = min(max(ix, 0), Ww - 1);
                idx_s[cr][t] = cy * Ww + cx;
                wgt_s[cr][t] = ok ? (wy * wx * m) : 0.f;
            }
        }
        // ---- 2. stage weights for this k (all threads) ----
        {
            const int4* src = (const int4*)(wb + (size_t)k * 128 * 128);
#pragma unroll
            for (int i = 0; i < 8; ++i) {
                int ci = i * 256 + t;            // 16B chunk id, 0..2047
                int o = ci >> 4;                 // 16 chunks per o-row
                int byte = (ci << 4) ^ ((o & 7) << 4);
                *(int4*)((char*)w_lds + byte) = src[ci];
            }
        }
        __syncthreads();

        // ---- 3. gather into val_lds: wave = 16 px; lane = (px pair, c-quad) ----
        {
            const int cq = lane & 31;
#pragma unroll
            for (int pp = 0; pp < 16; pp += 2) {
                int pxl = pm + pp + (lane >> 5);
                float w0 = wgt_s[0][pxl], w1 = wgt_s[1][pxl];
                float w2 = wgt_s[2][pxl], w3 = wgt_s[3][pxl];
                size_t i0 = (size_t)idx_s[0][pxl] * Cc;
                size_t i1 = (size_t)idx_s[1][pxl] * Cc;
                size_t i2 = (size_t)idx_s[2][pxl] * Cc;
                size_t i3 = (size_t)idx_s[3][pxl] * Cc;
                short4 v0 = *(const short4*)(xb + i0);
                short4 v1 = *(const short4*)(xb + i1);
                short4 v2 = *(const short4*)(xb + i2);
                short4 v3 = *(const short4*)(xb + i3);
                float s0 = w0 * bf2f(v0.x) + w1 * bf2f(v1.x) + w2 * bf2f(v2.x) + w3 * bf2f(v3.x);
                float s1 = w0 * bf2f(v0.y) + w1 * bf2f(v1.y) + w2 * bf2f(v2.y) + w3 * bf2f(v3.y);
                float s2 = w0 * bf2f(v0.z) + w1 * bf2f(v1.z) + w2 * bf2f(v2.z) + w3 * bf2f(v3.z);
                float s3 = w0 * bf2f(v0.w) + w1 * bf2f(v1.w) + w2 * bf2f(v2.w) + w3 * bf2f(v3.w);
                short4 r;
                r.x = f2bf(s0); r.y = f2bf(s1); r.z = f2bf(s2); r.w = f2bf(s3);
                int byte = (pxl * 256 + cq * 8) ^ ((pxl & 7) << 4);
                *(short4*)((char*)val_lds + byte) = r;
            }
        }
        __syncthreads();

        // ---- 4. MFMA: wave computes px[pm..pm+15] x o[0..127] ----
        {
            s16x8 afr[4];
            const int pxr = pm + (lane & 15);
            const int kb = (lane >> 4) * 8;       // k-slice base within 32
#pragma unroll
            for (int kk = 0; kk < 4; ++kk) {
                int byte = (pxr * 256 + (kk * 32 + kb) * 2) ^ ((pxr & 7) << 4);
                afr[kk] = *(const s16x8*)((char*)val_lds + byte);
            }
            const int orow = lane & 15;
#pragma unroll
            for (int ot = 0; ot < 8; ++ot) {
                int o = ot * 16 + orow;
#pragma unroll
                for (int kk = 0; kk < 4; ++kk) {
                    int byte = (o * 256 + (kk * 32 + kb) * 2) ^ ((o & 7) << 4);
                    s16x8 bfr = *(const s16x8*)((char*)w_lds + byte);
                    acc[ot] = __builtin_amdgcn_mfma_f32_16x16x32_bf16(afr[kk], bfr, acc[ot], 0, 0, 0);
                }
            }
        }
        __syncthreads();
    }

    // ---- epilogue: D layout col=lane&15 (o), row=(lane>>4)*4+reg (px) ----
#pragma unroll
    for (int ot = 0; ot < 8; ++ot) {
        int o = ot * 16 + (lane & 15);
        float bo = bias[o];
        float4 r;
        r.x = acc[ot][0] + bo;
        r.y = acc[ot][1] + bo;
        r.z = acc[ot][2] + bo;
        r.w = acc[ot][3] + bo;
        *(float4*)(out + ((size_t)(b * On + o)) * HW + p0 + pm + (lane >> 4) * 4) = r;
    }
}

// ---------------------------------------------------------------------------
extern "C" void kernel_launch(void* const* d_in, const int* in_sizes, int n_in,
                              void* d_out, int out_size, void* d_ws, size_t ws_size,
                              hipStream_t stream) {
    const float* x      = (const float*)d_in[0];
    const float* w_off  = (const float*)d_in[1];
    const float* b_off  = (const float*)d_in[2];
    const float* w_mask = (const float*)d_in[3];
    const float* b_mask = (const float*)d_in[4];
    const float* wt     = (const float*)d_in[5];
    const float* bias   = (const float*)d_in[6];
    float* out = (float*)d_out;

    short* xT  = (short*)d_ws;                      // B*HW*C bf16 hi  = 26.2 MB
    short* xLo = xT + (size_t)Bn * HW * Cc;         // B*HW*C bf16 lo  = 26.2 MB
    short* wb  = xLo + (size_t)Bn * HW * Cc;        // K*O*C bf16
    short* wofm_h = wb + Kk * On * Cc;              // 9*32*128
    short* wofm_l = wofm_h + Kk * 32 * Cc;          // 9*32*128
    float* dy = (float*)(wofm_l + Kk * 32 * Cc);    // B*9*HW f32
    float* dx = dy + (size_t)Bn * 9 * HW;
    float* mk = dx + (size_t)Bn * 9 * HW;
    // total ws: ~64 MB

    to_nhwc<<<dim3(HW / 64, Bn), 256, 0, stream>>>(x, xT, xLo);
    prep_w<<<(Kk * On * Cc + 255) / 256, 256, 0, stream>>>(wt, wb);
    prep_wofm<<<(Kk * 32 * Cc + 255) / 256, 256, 0, stream>>>(w_off, w_mask, wofm_h, wofm_l);
    offmask_mfma<<<dim3(Ww / 16, Hh / 4, Bn), 256, 0, stream>>>(
        xT, xLo, wofm_h, wofm_l, b_off, b_mask, dy, dx, mk);
    dconv_main<<<dim3(HW / 64, Bn), 256, 0, stream>>>(
        xT, wb, bias, dy, dx, mk, out);
}

// Round 5
// 348.013 us; speedup vs baseline: 4.2179x; 1.0864x over previous
//
#include <hip/hip_runtime.h>
#include <math.h>

constexpr int Bn = 4, Cc = 128, On = 128, Hh = 160, Ww = 160, Kk = 9;
constexpr int HW = Hh * Ww;          // 25600

typedef __attribute__((ext_vector_type(8))) short s16x8;
typedef __attribute__((ext_vector_type(4))) float f32x4;

__device__ inline float bf2f(short s) {
    union { float f; unsigned u; } v;
    v.u = ((unsigned)(unsigned short)s) << 16;
    return v.f;
}
__device__ inline short f2bf(float f) {
    union { float f; unsigned u; } v;
    v.f = f;
    unsigned r = v.u + 0x7fffu + ((v.u >> 16) & 1u);   // RNE
    return (short)(r >> 16);
}

// ---------------------------------------------------------------------------
// Kernel A1: x (NCHW f32) -> xT (NHWC bf16 hi) + xLo (NHWC bf16 lo).
// ---------------------------------------------------------------------------
__global__ __launch_bounds__(256) void to_nhwc(const float* __restrict__ x,
                                               short* __restrict__ xT,
                                               short* __restrict__ xLo) {
    __shared__ float tile[128][65];
    const int t = threadIdx.x;
    const int p0 = blockIdx.x * 64;
    const int b = blockIdx.y;
#pragma unroll
    for (int i = 0; i < 32; ++i) {
        int c = i * 4 + (t >> 6);
        tile[c][t & 63] = x[((size_t)b * Cc + c) * HW + p0 + (t & 63)];
    }
    __syncthreads();
    const int px = t >> 2, cq = t & 3;
    short* dsth = xT  + ((size_t)(b * HW) + p0 + px) * Cc;
    short* dstl = xLo + ((size_t)(b * HW) + p0 + px) * Cc;
#pragma unroll
    for (int j = 0; j < 8; ++j) {
        int c0 = cq * 4 + j * 16;
        short4 vh, vl;
        float f0 = tile[c0 + 0][px], f1 = tile[c0 + 1][px];
        float f2 = tile[c0 + 2][px], f3 = tile[c0 + 3][px];
        vh.x = f2bf(f0); vh.y = f2bf(f1); vh.z = f2bf(f2); vh.w = f2bf(f3);
        vl.x = f2bf(f0 - bf2f(vh.x));
        vl.y = f2bf(f1 - bf2f(vh.y));
        vl.z = f2bf(f2 - bf2f(vh.z));
        vl.w = f2bf(f3 - bf2f(vh.w));
        *(short4*)(dsth + c0) = vh;
        *(short4*)(dstl + c0) = vl;
    }
}

// ---------------------------------------------------------------------------
// Kernel A2: wt (O,C,3,3) f32 -> wb[k][o][c] bf16
// ---------------------------------------------------------------------------
__global__ void prep_w(const float* __restrict__ wt, short* __restrict__ wb) {
    int idx = blockIdx.x * 256 + threadIdx.x;     // K*O*C = 147456
    if (idx >= Kk * On * Cc) return;
    int c = idx & 127;
    int o = (idx >> 7) & 127;
    int k = idx >> 14;
    wb[idx] = f2bf(wt[(o * Cc + c) * 9 + k]);
}

// ---------------------------------------------------------------------------
// Kernel A3: offset/mask weights -> wofm_{hi,lo}[k][ch32][c].
// ---------------------------------------------------------------------------
__global__ void prep_wofm(const float* __restrict__ w_off,
                          const float* __restrict__ w_mask,
                          short* __restrict__ wh, short* __restrict__ wl) {
    int idx = blockIdx.x * 256 + threadIdx.x;     // 9*32*128 = 36864
    if (idx >= Kk * 32 * Cc) return;
    int c = idx & 127;
    int ch = (idx >> 7) & 31;
    int k = idx >> 12;
    float v = 0.f;
    if (ch < 18)      v = w_off[(ch * Cc + c) * 9 + k];
    else if (ch < 27) v = w_mask[((ch - 18) * Cc + c) * 9 + k];
    short hi = f2bf(v);
    wh[idx] = hi;
    wl[idx] = f2bf(v - bf2f(hi));
}

// ---------------------------------------------------------------------------
// Kernel B: offset/mask conv via MFMA with bf16 hi/lo split (unchanged r3).
// ---------------------------------------------------------------------------
__global__ __launch_bounds__(256) void offmask_mfma(
    const short* __restrict__ xT, const short* __restrict__ xLo,
    const short* __restrict__ wh, const short* __restrict__ wl,
    const float* __restrict__ b_off, const float* __restrict__ b_mask,
    float* __restrict__ dy_o, float* __restrict__ dx_o, float* __restrict__ mk_o)
{
    __shared__ short a_hi[6][2304];   // [slot][18px * 128c], row stride 256 B
    __shared__ short a_lo[6][2304];

    const int t = threadIdx.x;
    const int w0 = blockIdx.x * 16;
    const int h0 = blockIdx.y * 4;
    const int b = blockIdx.z;

    const short* xh_b = xT  + (size_t)b * HW * Cc;
    const short* xl_b = xLo + (size_t)b * HW * Cc;
#pragma unroll
    for (int j = 0; j < 14; ++j) {
        int ci = j * 256 + t;
        if (ci < 3456) {
            int slot = ci / 576;
            int rem  = ci % 576;
            int isLo = rem >= 288;
            int cj   = isLo ? rem - 288 : rem;
            int pxl  = cj >> 4;
            int ck   = cj & 15;
            int r   = h0 - 1 + slot;
            int col = w0 - 1 + pxl;
            int4 v = make_int4(0, 0, 0, 0);
            if ((unsigned)r < (unsigned)Hh && (unsigned)col < (unsigned)Ww) {
                const short* src = (isLo ? xl_b : xh_b) +
                                   ((size_t)(r * Ww + col)) * Cc + ck * 8;
                v = *(const int4*)src;
            }
            int byte = (pxl * 256 + ck * 16) ^ ((pxl & 7) << 4);
            *(int4*)((char*)(isLo ? a_lo[slot] : a_hi[slot]) + byte) = v;
        }
    }
    __syncthreads();

    const int lane = t & 63, wid = t >> 6;
    const int i  = lane & 15;
    const int kb = (lane >> 4) * 8;

    f32x4 acc[2];
    acc[0] = (f32x4){0.f, 0.f, 0.f, 0.f};
    acc[1] = (f32x4){0.f, 0.f, 0.f, 0.f};

#pragma unroll
    for (int ky = 0; ky < 3; ++ky) {
        const int slot = wid + ky;
#pragma unroll
        for (int kxi = 0; kxi < 3; ++kxi) {
            const int pxl = i + kxi;
            s16x8 ah[4], al[4];
#pragma unroll
            for (int kk = 0; kk < 4; ++kk) {
                int byte = (pxl * 256 + (kk * 32 + kb) * 2) ^ ((pxl & 7) << 4);
                ah[kk] = *(const s16x8*)((char*)a_hi[slot] + byte);
                al[kk] = *(const s16x8*)((char*)a_lo[slot] + byte);
            }
            const int k = ky * 3 + kxi;
#pragma unroll
            for (int tile = 0; tile < 2; ++tile) {
                const short* bp = wh + ((size_t)k * 32 + tile * 16 + i) * Cc + kb;
                const short* lp = wl + ((size_t)k * 32 + tile * 16 + i) * Cc + kb;
                s16x8 bh[4], bl[4];
#pragma unroll
                for (int kk = 0; kk < 4; ++kk) {
                    bh[kk] = *(const s16x8*)(bp + kk * 32);
                    bl[kk] = *(const s16x8*)(lp + kk * 32);
                }
#pragma unroll
                for (int kk = 0; kk < 4; ++kk) {
                    acc[tile] = __builtin_amdgcn_mfma_f32_16x16x32_bf16(ah[kk], bh[kk], acc[tile], 0, 0, 0);
                    acc[tile] = __builtin_amdgcn_mfma_f32_16x16x32_bf16(al[kk], bh[kk], acc[tile], 0, 0, 0);
                    acc[tile] = __builtin_amdgcn_mfma_f32_16x16x32_bf16(ah[kk], bl[kk], acc[tile], 0, 0, 0);
                }
            }
        }
    }

    const int hr = h0 + wid;
#pragma unroll
    for (int tile = 0; tile < 2; ++tile) {
        int ch = tile * 16 + i;
#pragma unroll
        for (int reg = 0; reg < 4; ++reg) {
            int pxo = (lane >> 4) * 4 + reg;
            int p = hr * Ww + w0 + pxo;
            float v = acc[tile][reg];
            if (ch < 18) {
                int k = ch >> 1;
                v += b_off[ch];
                if (ch & 1) dx_o[(size_t)(b * 9 + k) * HW + p] = v;
                else        dy_o[(size_t)(b * 9 + k) * HW + p] = v;
            } else if (ch < 27) {
                int k = ch - 18;
                v += b_mask[k];
                mk_o[(size_t)(b * 9 + k) * HW + p] = 1.f / (1.f + expf(-v));
            }
        }
    }
}

// ---------------------------------------------------------------------------
// Kernel C: main deformable conv (r3-proven body) with TWO deltas only:
//  (1) XCD-chunked block swizzle: flat 1600-block grid, 200 contiguous
//      (b,tile) pairs per XCD -> gather window stays L2-resident.
//  (2) per-k bilinear setup uses all 256 threads (64 px x 4 corners)
//      instead of 64 threads x 4 corners serially.
// Sync structure, LDS layout, MFMA code: byte-identical to round 3.
// ---------------------------------------------------------------------------
__global__ __launch_bounds__(256) void dconv_main(
    const short* __restrict__ xT,    // [b][hw][c] bf16
    const short* __restrict__ wb,    // [k][o][c] bf16
    const float* __restrict__ bias,
    const float* __restrict__ dy_i, const float* __restrict__ dx_i,
    const float* __restrict__ mk_i,
    float* __restrict__ out)
{
    __shared__ short w_lds[128 * 128];   // 32 KB, byte ^= (o&7)<<4
    __shared__ short val_lds[64 * 128];  // 16 KB, byte ^= (px&7)<<4
    __shared__ float wgt_s[4][64];
    __shared__ int   idx_s[4][64];

    // XCD-chunked swizzle: 1600 blocks = 8 XCDs x 200 contiguous (b,tile).
    const int g = blockIdx.x;
    const int orig = (g & 7) * 200 + (g >> 3);
    const int b = orig / 400;
    const int p0 = (orig % 400) * 64;

    const int t = threadIdx.x;
    const int lane = t & 63;
    const int wid = t >> 6;
    const int pm = wid * 16;             // wave's pixel base

    f32x4 acc[8];
#pragma unroll
    for (int i = 0; i < 8; ++i) acc[i] = (f32x4){0.f, 0.f, 0.f, 0.f};

    const short* xb = xT + (size_t)b * HW * Cc + (lane & 31) * 4;

    for (int k = 0; k < Kk; ++k) {
        // ---- 1. bilinear setup: 256 threads = 64 px x 4 corners ----
        {
            int px = t & 63;
            int cr = t >> 6;
            int p = p0 + px;
            int h = p / Ww, w = p % Ww;
            size_t base = (size_t)(b * 9 + k) * HW + p;
            float dyv = dy_i[base], dxv = dx_i[base], m = mk_i[base];
            float py  = (float)(h + (k / 3) - 1) + dyv;
            float pxf = (float)(w + (k % 3) - 1) + dxv;
            float y0f = floorf(py), x0f = floorf(pxf);
            float ly = py - y0f, lx = pxf - x0f;
            int y0 = (int)y0f, x0 = (int)x0f;
            int iy = y0 + (cr >> 1), ix = x0 + (cr & 1);
            bool ok = ((unsigned)iy < (unsigned)Hh) && ((unsigned)ix < (unsigned)Ww);
            float wy = (cr >> 1) ? ly : (1.f - ly);
            float wx = (cr & 1) ? lx : (1.f - lx);
            int cy = min(max(iy, 0), Hh - 1);
            int cx = min(max(ix, 0), Ww - 1);
            idx_s[cr][px] = cy * Ww + cx;
            wgt_s[cr][px] = ok ? (wy * wx * m) : 0.f;
        }
        // ---- 2. stage weights for this k (all threads) ----
        {
            const int4* src = (const int4*)(wb + (size_t)k * 128 * 128);
#pragma unroll
            for (int i = 0; i < 8; ++i) {
                int ci = i * 256 + t;            // 16B chunk id, 0..2047
                int o = ci >> 4;                 // 16 chunks per o-row
                int byte = (ci << 4) ^ ((o & 7) << 4);
                *(int4*)((char*)w_lds + byte) = src[ci];
            }
        }
        __syncthreads();

        // ---- 3. gather into val_lds: wave = 16 px; lane = (px pair, c-quad) ----
        {
            const int cq = lane & 31;
#pragma unroll
            for (int pp = 0; pp < 16; pp += 2) {
                int pxl = pm + pp + (lane >> 5);
                float w0 = wgt_s[0][pxl], w1 = wgt_s[1][pxl];
                float w2 = wgt_s[2][pxl], w3 = wgt_s[3][pxl];
                size_t i0 = (size_t)idx_s[0][pxl] * Cc;
                size_t i1 = (size_t)idx_s[1][pxl] * Cc;
                size_t i2 = (size_t)idx_s[2][pxl] * Cc;
                size_t i3 = (size_t)idx_s[3][pxl] * Cc;
                short4 v0 = *(const short4*)(xb + i0);
                short4 v1 = *(const short4*)(xb + i1);
                short4 v2 = *(const short4*)(xb + i2);
                short4 v3 = *(const short4*)(xb + i3);
                float s0 = w0 * bf2f(v0.x) + w1 * bf2f(v1.x) + w2 * bf2f(v2.x) + w3 * bf2f(v3.x);
                float s1 = w0 * bf2f(v0.y) + w1 * bf2f(v1.y) + w2 * bf2f(v2.y) + w3 * bf2f(v3.y);
                float s2 = w0 * bf2f(v0.z) + w1 * bf2f(v1.z) + w2 * bf2f(v2.z) + w3 * bf2f(v3.z);
                float s3 = w0 * bf2f(v0.w) + w1 * bf2f(v1.w) + w2 * bf2f(v2.w) + w3 * bf2f(v3.w);
                short4 r;
                r.x = f2bf(s0); r.y = f2bf(s1); r.z = f2bf(s2); r.w = f2bf(s3);
                int byte = (pxl * 256 + cq * 8) ^ ((pxl & 7) << 4);
                *(short4*)((char*)val_lds + byte) = r;
            }
        }
        __syncthreads();

        // ---- 4. MFMA: wave computes px[pm..pm+15] x o[0..127] ----
        {
            s16x8 afr[4];
            const int pxr = pm + (lane & 15);
            const int kb = (lane >> 4) * 8;       // k-slice base within 32
#pragma unroll
            for (int kk = 0; kk < 4; ++kk) {
                int byte = (pxr * 256 + (kk * 32 + kb) * 2) ^ ((pxr & 7) << 4);
                afr[kk] = *(const s16x8*)((char*)val_lds + byte);
            }
            const int orow = lane & 15;
#pragma unroll
            for (int ot = 0; ot < 8; ++ot) {
                int o = ot * 16 + orow;
#pragma unroll
                for (int kk = 0; kk < 4; ++kk) {
                    int byte = (o * 256 + (kk * 32 + kb) * 2) ^ ((o & 7) << 4);
                    s16x8 bfr = *(const s16x8*)((char*)w_lds + byte);
                    acc[ot] = __builtin_amdgcn_mfma_f32_16x16x32_bf16(afr[kk], bfr, acc[ot], 0, 0, 0);
                }
            }
        }
        __syncthreads();
    }

    // ---- epilogue: D layout col=lane&15 (o), row=(lane>>4)*4+reg (px) ----
#pragma unroll
    for (int ot = 0; ot < 8; ++ot) {
        int o = ot * 16 + (lane & 15);
        float bo = bias[o];
        float4 r;
        r.x = acc[ot][0] + bo;
        r.y = acc[ot][1] + bo;
        r.z = acc[ot][2] + bo;
        r.w = acc[ot][3] + bo;
        *(float4*)(out + ((size_t)(b * On + o)) * HW + p0 + pm + (lane >> 4) * 4) = r;
    }
}

// ---------------------------------------------------------------------------
extern "C" void kernel_launch(void* const* d_in, const int* in_sizes, int n_in,
                              void* d_out, int out_size, void* d_ws, size_t ws_size,
                              hipStream_t stream) {
    const float* x      = (const float*)d_in[0];
    const float* w_off  = (const float*)d_in[1];
    const float* b_off  = (const float*)d_in[2];
    const float* w_mask = (const float*)d_in[3];
    const float* b_mask = (const float*)d_in[4];
    const float* wt     = (const float*)d_in[5];
    const float* bias   = (const float*)d_in[6];
    float* out = (float*)d_out;

    short* xT  = (short*)d_ws;                      // B*HW*C bf16 hi
    short* xLo = xT + (size_t)Bn * HW * Cc;         // B*HW*C bf16 lo
    short* wb  = xLo + (size_t)Bn * HW * Cc;        // K*O*C bf16
    short* wofm_h = wb + Kk * On * Cc;
    short* wofm_l = wofm_h + Kk * 32 * Cc;
    float* dy = (float*)(wofm_l + Kk * 32 * Cc);
    float* dx = dy + (size_t)Bn * 9 * HW;
    float* mk = dx + (size_t)Bn * 9 * HW;

    to_nhwc<<<dim3(HW / 64, Bn), 256, 0, stream>>>(x, xT, xLo);
    prep_w<<<(Kk * On * Cc + 255) / 256, 256, 0, stream>>>(wt, wb);
    prep_wofm<<<(Kk * 32 * Cc + 255) / 256, 256, 0, stream>>>(w_off, w_mask, wofm_h, wofm_l);
    offmask_mfma<<<dim3(Ww / 16, Hh / 4, Bn), 256, 0, stream>>>(
        xT, xLo, wofm_h, wofm_l, b_off, b_mask, dy, dx, mk);
    dconv_main<<<1600, 256, 0, stream>>>(
        xT, wb, bias, dy, dx, mk, out);
}